// Round 1
// 1408.189 us; speedup vs baseline: 1.1534x; 1.1534x over previous
//
#include <hip/hip_runtime.h>
#include <math.h>

#define NN 50000
#define EE 800000
#define EPS 1e-5f
#define SCAN_CH 196   // ceil(NN/256)

#define NEG_BIG (-1e30f)
#define RESCALE_THR 4.0f

// ---------------------------------------------------------------------------
// CSR build: histogram -> 3-kernel parallel scan -> scatter (packs src+ea)
// ---------------------------------------------------------------------------
__global__ void hist_kernel(const int* __restrict__ dst, int* cnt) {
    int e = blockIdx.x * blockDim.x + threadIdx.x;
    if (e < EE) atomicAdd(&cnt[dst[e]], 1);
}

// 256 blocks x 256 thr: block b reduces cnt[b*196 .. b*196+195] -> part[b]
__global__ void scan_part(const int* __restrict__ cnt, int* __restrict__ part) {
    __shared__ int red[256];
    int b = blockIdx.x, t = threadIdx.x;
    int i = b * SCAN_CH + t;
    int v = (t < SCAN_CH && i < NN) ? cnt[i] : 0;
    red[t] = v;
    __syncthreads();
#pragma unroll
    for (int s = 128; s; s >>= 1) {
        if (t < s) red[t] += red[t + s];
        __syncthreads();
    }
    if (t == 0) part[b] = red[0];
}

// 1 block: exclusive scan of 256 partials
__global__ void scan_block(int* part) {
    __shared__ int buf[2][256];
    int t = threadIdx.x;
    int v = part[t];
    int p = 0;
    buf[0][t] = v;
    __syncthreads();
#pragma unroll
    for (int off = 1; off < 256; off <<= 1) {
        buf[p ^ 1][t] = buf[p][t] + ((t >= off) ? buf[p][t - off] : 0);
        __syncthreads();
        p ^= 1;
    }
    part[t] = buf[p][t] - v;
}

// 256 blocks: in-block inclusive scan + block offset -> row_start & cursor
__global__ void scan_final(int* __restrict__ cntcur, const int* __restrict__ part,
                           int* __restrict__ row_start) {
    __shared__ int buf[2][256];
    int b = blockIdx.x, t = threadIdx.x;
    int i = b * SCAN_CH + t;
    int v = (t < SCAN_CH && i < NN) ? cntcur[i] : 0;
    int p = 0;
    buf[0][t] = v;
    __syncthreads();
#pragma unroll
    for (int off = 1; off < 256; off <<= 1) {
        buf[p ^ 1][t] = buf[p][t] + ((t >= off) ? buf[p][t - off] : 0);
        __syncthreads();
        p ^= 1;
    }
    if (t < SCAN_CH && i < NN) {
        int pos = part[b] + buf[p][t] - v;   // exclusive
        row_start[i] = pos;
        cntcur[i] = pos;                     // scatter cursor
    }
    if (b == 0 && t == 0) row_start[NN] = EE;
}

__global__ void scatter_kernel(const int* __restrict__ ei, const float* __restrict__ ea,
                               int* cursor, int2* __restrict__ edge_pack) {
    int e = blockIdx.x * blockDim.x + threadIdx.x;
    if (e < EE) {
        int d = ei[EE + e];
        int pos = atomicAdd(&cursor[d], 1);
        edge_pack[pos] = make_int2(ei[e], __float_as_int(ea[e]));
    }
}

// ---------------------------------------------------------------------------
// Fused dual GEMM with register prefetch of next K-tile.
// C[M x 256] = A[M x 128] @ [Wl | Wr]; 128x128 tile, 8x8 micro, K-tile 32.
// ---------------------------------------------------------------------------
#define LDP 132
__global__ __launch_bounds__(256) void gemm_dual(const float* __restrict__ A,
                                                 const float* __restrict__ Wl,
                                                 const float* __restrict__ Wr,
                                                 float* __restrict__ C, int M) {
    __shared__ float As[32][LDP];
    __shared__ float Bs[32][LDP];
    const float* B = blockIdx.y ? Wr : Wl;
    int coff = blockIdx.y << 7;
    int t  = threadIdx.x;
    int bm = blockIdx.x * 128;
    int tx = t & 15, ty = t >> 4;

    int kk  = (t & 7) * 4;   // A-load: k within tile
    int row = t >> 3;        // A-load: base row
    int cc  = (t & 31) * 4;  // B-load: col
    int kr  = t >> 5;        // B-load: base k

    float acc[8][8];
#pragma unroll
    for (int i = 0; i < 8; ++i)
#pragma unroll
        for (int j = 0; j < 8; ++j) acc[i][j] = 0.f;

    float4 pa[4], pb[4];
#pragma unroll
    for (int p = 0; p < 4; ++p) {
        int gm = bm + row + p * 32;
        pa[p] = (gm < M) ? *(const float4*)(A + (size_t)gm * 128 + kk)
                         : make_float4(0.f, 0.f, 0.f, 0.f);
        pb[p] = *(const float4*)(B + (size_t)(kr + p * 8) * 128 + cc);
    }

    for (int kt = 0; kt < 4; ++kt) {
#pragma unroll
        for (int p = 0; p < 4; ++p) {
            int r = row + p * 32;
            As[kk + 0][r] = pa[p].x; As[kk + 1][r] = pa[p].y;
            As[kk + 2][r] = pa[p].z; As[kk + 3][r] = pa[p].w;
            *(float4*)&Bs[kr + p * 8][cc] = pb[p];
        }
        __syncthreads();
        if (kt < 3) {
            int k0 = (kt + 1) * 32;
#pragma unroll
            for (int p = 0; p < 4; ++p) {
                int gm = bm + row + p * 32;
                pa[p] = (gm < M) ? *(const float4*)(A + (size_t)gm * 128 + k0 + kk)
                                 : make_float4(0.f, 0.f, 0.f, 0.f);
                pb[p] = *(const float4*)(B + (size_t)(k0 + kr + p * 8) * 128 + cc);
            }
        }
#pragma unroll
        for (int k = 0; k < 32; ++k) {
            float4 A0 = *(const float4*)&As[k][ty * 4];
            float4 A1 = *(const float4*)&As[k][64 + ty * 4];
            float4 B0 = *(const float4*)&Bs[k][tx * 4];
            float4 B1 = *(const float4*)&Bs[k][64 + tx * 4];
            float av[8] = {A0.x, A0.y, A0.z, A0.w, A1.x, A1.y, A1.z, A1.w};
            float bv[8] = {B0.x, B0.y, B0.z, B0.w, B1.x, B1.y, B1.z, B1.w};
#pragma unroll
            for (int i = 0; i < 8; ++i)
#pragma unroll
                for (int j = 0; j < 8; ++j)
                    acc[i][j] = fmaf(av[i], bv[j], acc[i][j]);
        }
        __syncthreads();
    }

#pragma unroll
    for (int i = 0; i < 8; ++i) {
        int r = bm + ((i < 4) ? (ty * 4 + i) : (64 + ty * 4 + i - 4));
        if (r < M) {
            float* crow = C + (size_t)r * 256 + coff;
            *(float4*)(crow + tx * 4)      = make_float4(acc[i][0], acc[i][1], acc[i][2], acc[i][3]);
            *(float4*)(crow + 64 + tx * 4) = make_float4(acc[i][4], acc[i][5], acc[i][6], acc[i][7]);
        }
    }
}

// ---------------------------------------------------------------------------
// Small fp32 GEMM for layer 10 (A stride 128, nc<=64)
// ---------------------------------------------------------------------------
__global__ __launch_bounds__(256) void gemm_tile(const float* __restrict__ A,
                                                 const float* __restrict__ B,
                                                 float* __restrict__ C,
                                                 int M, int nc, int ldb, int ldc, int coff) {
    __shared__ float As[128][64];
    __shared__ float Bs[128][64];
    int t  = threadIdx.x;
    int bm = blockIdx.x * 64;
    int bn = blockIdx.y * 64;
    {
        int k4 = (t & 31) << 2;
        int r0 = t >> 5;
#pragma unroll
        for (int pass = 0; pass < 8; ++pass) {
            int row = r0 + pass * 8;
            int gm  = bm + row;
            float4 v = make_float4(0.f, 0.f, 0.f, 0.f);
            if (gm < M) v = *(const float4*)(A + (size_t)gm * 128 + k4);
            As[k4 + 0][row] = v.x; As[k4 + 1][row] = v.y;
            As[k4 + 2][row] = v.z; As[k4 + 3][row] = v.w;
        }
    }
    {
        int c4 = (t & 15) << 2;
        int kr = t >> 4;
#pragma unroll
        for (int pass = 0; pass < 8; ++pass) {
            int k  = kr + pass * 16;
            int gc = bn + c4;
            float4 v = make_float4(0.f, 0.f, 0.f, 0.f);
            if (gc < nc) v = *(const float4*)(B + (size_t)k * ldb + gc);
            *(float4*)&Bs[k][c4] = v;
        }
    }
    __syncthreads();

    int tx = t & 15, ty = t >> 4;
    int m0 = ty * 4, c0 = tx * 4;
    float acc[4][4] = {{0.f}};
#pragma unroll 8
    for (int k = 0; k < 128; ++k) {
        float4 av = *(const float4*)&As[k][m0];
        float4 bv = *(const float4*)&Bs[k][c0];
        float a4[4] = {av.x, av.y, av.z, av.w};
        float b4[4] = {bv.x, bv.y, bv.z, bv.w};
#pragma unroll
        for (int i = 0; i < 4; ++i)
#pragma unroll
            for (int j = 0; j < 4; ++j) acc[i][j] = fmaf(a4[i], b4[j], acc[i][j]);
    }
#pragma unroll
    for (int i = 0; i < 4; ++i) {
        int gm = bm + m0 + i;
        int gc = bn + c0;
        if (gm < M && gc < nc) {
            *(float4*)(C + (size_t)gm * ldc + coff + gc) =
                make_float4(acc[i][0], acc[i][1], acc[i][2], acc[i][3]);
        }
    }
}

// ---------------------------------------------------------------------------
// Node kernel layers 1-9 (rewritten):
//   - one wave/node, HALF-WAVE per edge (2 edges per wave-instruction)
//   - float4 gather per lane (4 contiguous channels; 32 lanes cover 128)
//   - 8-lane head reduction via DPP-fused v_add_f32 (no ds_swizzle)
//   - defer-max online softmax (rescale only when p > mx + THR, wave-uniform
//     ballot branch); sentinel -1e30 avoids inf-inf NaNs; phantom tail
//     contributions carry mx=-1e30 and are annihilated at state merge
// ---------------------------------------------------------------------------
__device__ __forceinline__ float dpp_add8(float x) {
    // sum over each aligned 8-lane group: xor1 (quad_perm[1,0,3,2]),
    // xor2 (quad_perm[2,3,0,1]), xor7 (row_half_mirror)
    int t;
    t = __builtin_amdgcn_update_dpp(0, __float_as_int(x), 0xB1, 0xf, 0xf, true);
    x += __int_as_float(t);
    t = __builtin_amdgcn_update_dpp(0, __float_as_int(x), 0x4E, 0xf, 0xf, true);
    x += __int_as_float(t);
    t = __builtin_amdgcn_update_dpp(0, __float_as_int(x), 0x141, 0xf, 0xf, true);
    x += __int_as_float(t);
    return x;
}

__global__ __launch_bounds__(256) void node_agg_128(const float* __restrict__ xlr,
                                                    const int* __restrict__ row_start,
                                                    const int2* __restrict__ epack,
                                                    const float* __restrict__ We,
                                                    const float* __restrict__ att,
                                                    const float* __restrict__ bias,
                                                    const float* __restrict__ bng,
                                                    const float* __restrict__ bnb,
                                                    const float* __restrict__ bnm,
                                                    const float* __restrict__ bnv,
                                                    float* __restrict__ hout) {
    int wave = (blockIdx.x * blockDim.x + threadIdx.x) >> 6;
    int lane = threadIdx.x & 63;
    if (wave >= NN) return;
    int half = lane >> 5;          // which edge of the pair this lane handles
    int c0   = (lane & 31) << 2;   // 4 contiguous channels per lane

    const float L2E = 1.44269504f;
    const float4 xr4 = *(const float4*)(xlr + (size_t)wave * 256 + 128 + c0);
    const float4 we4 = *(const float4*)(We + c0);
    const float4 at4 = *(const float4*)(att + c0);
    float4 a6, a4;
    a6.x = 0.6f * L2E * at4.x; a4.x = 0.4f * L2E * at4.x;
    a6.y = 0.6f * L2E * at4.y; a4.y = 0.4f * L2E * at4.y;
    a6.z = 0.6f * L2E * at4.z; a4.z = 0.4f * L2E * at4.z;
    a6.w = 0.6f * L2E * at4.w; a4.w = 0.4f * L2E * at4.w;

    int beg = row_start[wave], end = row_start[wave + 1];
    int lastE = end - 1;

    // 2 independent online-softmax states (per lane, per half)
    float mx0 = NEG_BIG, sm0 = 0.f;
    float mx1 = NEG_BIG, sm1 = 0.f;
    float4 ac0 = make_float4(0.f, 0.f, 0.f, 0.f);
    float4 ac1 = make_float4(0.f, 0.f, 0.f, 0.f);

    auto score = [&](float eav, const float4& xv) -> float {
        float m0 = xv.x + fmaf(eav, we4.x, xr4.x);
        float m1 = xv.y + fmaf(eav, we4.y, xr4.y);
        float m2 = xv.z + fmaf(eav, we4.z, xr4.z);
        float m3 = xv.w + fmaf(eav, we4.w, xr4.w);
        float p = fmaf(a6.x, m0, a4.x * fabsf(m0));
        p = fmaf(a6.y, m1, fmaf(a4.y, fabsf(m1), p));
        p = fmaf(a6.z, m2, fmaf(a4.z, fabsf(m2), p));
        p = fmaf(a6.w, m3, fmaf(a4.w, fabsf(m3), p));
        return dpp_add8(p);   // all 8 lanes of the head group hold the score
    };

    auto upd = [&](float& mx, float& sm, float4& ac, float p, const float4& xv) {
        float d = p - mx;
        if (__ballot(d > RESCALE_THR)) {   // wave-uniform slow path (rare)
            float nm = fmaxf(mx, p);
            float sc = exp2f(mx - nm);
            float w  = exp2f(p - nm);
            sm = fmaf(sm, sc, w);
            ac.x = fmaf(ac.x, sc, w * xv.x);
            ac.y = fmaf(ac.y, sc, w * xv.y);
            ac.z = fmaf(ac.z, sc, w * xv.z);
            ac.w = fmaf(ac.w, sc, w * xv.w);
            mx = nm;
        } else {                           // fast path: no rescale
            float w = exp2f(d);
            sm += w;
            ac.x = fmaf(w, xv.x, ac.x);
            ac.y = fmaf(w, xv.y, ac.y);
            ac.z = fmaf(w, xv.z, ac.z);
            ac.w = fmaf(w, xv.w, ac.w);
        }
    };

    int j = beg;
    // main loop: 4 real edges per iteration (2 pairs x 2 halves), no clamping
    for (; j + 3 < end; j += 4) {
        int2 pkA = epack[j + half];
        int2 pkB = epack[j + 2 + half];
        float4 xA = *(const float4*)(xlr + ((size_t)pkA.x << 8) + c0);
        float4 xB = *(const float4*)(xlr + ((size_t)pkB.x << 8) + c0);
        float pA = score(__int_as_float(pkA.y), xA);
        float pB = score(__int_as_float(pkB.y), xB);
        upd(mx0, sm0, ac0, pA, xA);
        upd(mx1, sm1, ac1, pB, xB);
    }
    // tail: up to 3 remaining edges, duplicated slots forced to NEG_BIG score
    if (j < end) {
        int jeA = j + half;       bool dA = jeA > lastE; if (dA) jeA = lastE;
        int jeB = j + 2 + half;   bool dB = jeB > lastE; if (dB) jeB = lastE;
        int2 pkA = epack[jeA];
        int2 pkB = epack[jeB];
        float4 xA = *(const float4*)(xlr + ((size_t)pkA.x << 8) + c0);
        float4 xB = *(const float4*)(xlr + ((size_t)pkB.x << 8) + c0);
        float pA = score(__int_as_float(pkA.y), xA);
        float pB = score(__int_as_float(pkB.y), xB);
        pA = dA ? NEG_BIG : pA;
        pB = dB ? NEG_BIG : pB;
        upd(mx0, sm0, ac0, pA, xA);
        upd(mx1, sm1, ac1, pB, xB);
    }

    // merge the 2 states in-lane
    float Mx = fmaxf(mx0, mx1);
    float s0 = exp2f(mx0 - Mx), s1 = exp2f(mx1 - Mx);
    float sm = fmaf(sm0, s0, sm1 * s1);
    float4 ac;
    ac.x = fmaf(ac0.x, s0, ac1.x * s1);
    ac.y = fmaf(ac0.y, s0, ac1.y * s1);
    ac.z = fmaf(ac0.z, s0, ac1.z * s1);
    ac.w = fmaf(ac0.w, s0, ac1.w * s1);

    // merge across halves (lanes l and l+32 hold the same channels)
    float  Mo  = __shfl_xor(Mx, 32);
    float  smo = __shfl_xor(sm, 32);
    float4 aco;
    aco.x = __shfl_xor(ac.x, 32);
    aco.y = __shfl_xor(ac.y, 32);
    aco.z = __shfl_xor(ac.z, 32);
    aco.w = __shfl_xor(ac.w, 32);
    float Mn = fmaxf(Mx, Mo);
    float ss = exp2f(Mx - Mn), so = exp2f(Mo - Mn);
    sm   = fmaf(sm, ss, smo * so);
    ac.x = fmaf(ac.x, ss, aco.x * so);
    ac.y = fmaf(ac.y, ss, aco.y * so);
    ac.z = fmaf(ac.z, ss, aco.z * so);
    ac.w = fmaf(ac.w, ss, aco.w * so);

    if (half == 0) {
        float inv = 1.f / (sm + 1e-16f);
        const float4 b4  = *(const float4*)(bias + c0);
        const float4 g4  = *(const float4*)(bng + c0);
        const float4 bb4 = *(const float4*)(bnb + c0);
        const float4 m4  = *(const float4*)(bnm + c0);
        const float4 v4  = *(const float4*)(bnv + c0);
        float4 y;
        y.x = fmaxf(fmaf(ac.x, inv, b4.x), 0.f);
        y.y = fmaxf(fmaf(ac.y, inv, b4.y), 0.f);
        y.z = fmaxf(fmaf(ac.z, inv, b4.z), 0.f);
        y.w = fmaxf(fmaf(ac.w, inv, b4.w), 0.f);
        y.x = (y.x - m4.x) * rsqrtf(v4.x + EPS) * g4.x + bb4.x;
        y.y = (y.y - m4.y) * rsqrtf(v4.y + EPS) * g4.y + bb4.y;
        y.z = (y.z - m4.z) * rsqrtf(v4.z + EPS) * g4.z + bb4.z;
        y.w = (y.w - m4.w) * rsqrtf(v4.w + EPS) * g4.w + bb4.w;
        *(float4*)(hout + (size_t)wave * 128 + c0) = y;
    }
}

// ---------------------------------------------------------------------------
// Layer 10: half-wave per node. H=1, C=32, xlr10: [N][64]. 2 states, unroll-2.
// ---------------------------------------------------------------------------
__global__ __launch_bounds__(256) void node_agg_l10(const float* __restrict__ xlr,
                                                    const int* __restrict__ row_start,
                                                    const int2* __restrict__ epack,
                                                    const float* __restrict__ We,
                                                    const float* __restrict__ att,
                                                    const float* __restrict__ bias,
                                                    const float* __restrict__ bng,
                                                    const float* __restrict__ bnb,
                                                    const float* __restrict__ bnm,
                                                    const float* __restrict__ bnv,
                                                    const float* __restrict__ linW,
                                                    const float* __restrict__ linb,
                                                    float* __restrict__ out) {
    int n = (blockIdx.x * blockDim.x + threadIdx.x) >> 5;
    int c = threadIdx.x & 31;
    if (n >= NN) return;

    const float L2E = 1.44269504f;
    float xr = xlr[(size_t)n * 64 + 32 + c];
    float we = We[c];
    float a6 = 0.6f * L2E * att[c], a4 = 0.4f * L2E * att[c];
    int beg = row_start[n], end = row_start[n + 1];

    float mxs[2] = {-INFINITY, -INFINITY};
    float sms[2] = {0.f, 0.f};
    float acs[2] = {0.f, 0.f};

    auto upd = [&](int st, float xl, float eav) {
        float m = xl + fmaf(eav, we, xr);
        float p = fmaf(a6, m, a4 * fabsf(m));
#pragma unroll
        for (int off = 16; off; off >>= 1) p += __shfl_xor(p, off);
        float nm = fmaxf(mxs[st], p);
        float sc = exp2f(mxs[st] - nm);
        float w  = exp2f(p - nm);
        sms[st] = fmaf(sms[st], sc, w);
        acs[st] = fmaf(acs[st], sc, w * xl);
        mxs[st] = nm;
    };

    int j = beg;
    for (; j + 1 < end; j += 2) {
        int2 p0 = epack[j], p1 = epack[j + 1];
        float x0 = xlr[((size_t)p0.x << 6) + c];
        float x1 = xlr[((size_t)p1.x << 6) + c];
        upd(0, x0, __int_as_float(p0.y));
        upd(1, x1, __int_as_float(p1.y));
    }
    if (j < end) {
        int2 pk = epack[j];
        upd(0, xlr[((size_t)pk.x << 6) + c], __int_as_float(pk.y));
    }

    float M = fmaxf(mxs[0], mxs[1]);
    float sm = 0.f, acc = 0.f;
#pragma unroll
    for (int st = 0; st < 2; ++st) {
        float sc = (mxs[st] == -INFINITY) ? 0.f : exp2f(mxs[st] - M);
        sm  = fmaf(sms[st], sc, sm);
        acc = fmaf(acs[st], sc, acc);
    }

    float y = acc / (sm + 1e-16f) + bias[c];
    y = fmaxf(y, 0.f);
    y = (y - bnm[c]) * rsqrtf(bnv[c] + EPS) * bng[c] + bnb[c];

    float t0 = y * linW[c * 4 + 0];
    float t1 = y * linW[c * 4 + 1];
    float t2 = y * linW[c * 4 + 2];
    float t3 = y * linW[c * 4 + 3];
#pragma unroll
    for (int off = 16; off; off >>= 1) {
        t0 += __shfl_xor(t0, off);
        t1 += __shfl_xor(t1, off);
        t2 += __shfl_xor(t2, off);
        t3 += __shfl_xor(t3, off);
    }
    if (c == 0) {
        out[(size_t)n * 4 + 0] = t0 + linb[0];
        out[(size_t)n * 4 + 1] = t1 + linb[1];
        out[(size_t)n * 4 + 2] = t2 + linb[2];
        out[(size_t)n * 4 + 3] = t3 + linb[3];
    }
}

// ---------------------------------------------------------------------------
extern "C" void kernel_launch(void* const* d_in, const int* in_sizes, int n_in,
                              void* d_out, int out_size, void* d_ws, size_t ws_size,
                              hipStream_t stream) {
    const float* x      = (const float*)d_in[0];
    const int*   ei     = (const int*)d_in[1];
    const float* ea     = (const float*)d_in[2];
    const float* l1_Wl  = (const float*)d_in[3];
    const float* l1_Wr  = (const float*)d_in[4];
    const float* l1_We  = (const float*)d_in[5];
    const float* l1_att = (const float*)d_in[6];
    const float* l1_b   = (const float*)d_in[7];
    const float* mid_Wl = (const float*)d_in[8];
    const float* mid_Wr = (const float*)d_in[9];
    const float* mid_We = (const float*)d_in[10];
    const float* mid_att= (const float*)d_in[11];
    const float* mid_b  = (const float*)d_in[12];
    const float* l10_Wl = (const float*)d_in[13];
    const float* l10_Wr = (const float*)d_in[14];
    const float* l10_We = (const float*)d_in[15];
    const float* l10_att= (const float*)d_in[16];
    const float* l10_b  = (const float*)d_in[17];
    const float* bn_g   = (const float*)d_in[18];
    const float* bn_b   = (const float*)d_in[19];
    const float* bn_m   = (const float*)d_in[20];
    const float* bn_v   = (const float*)d_in[21];
    const float* bn10_g = (const float*)d_in[22];
    const float* bn10_b = (const float*)d_in[23];
    const float* bn10_m = (const float*)d_in[24];
    const float* bn10_v = (const float*)d_in[25];
    const float* lin_W  = (const float*)d_in[26];
    const float* lin_b  = (const float*)d_in[27];

    char* ws = (char*)d_ws;
    auto take = [&](size_t bytes) { char* p = ws; ws += (bytes + 255) & ~size_t(255); return p; };
    int*   row_start  = (int*)  take(sizeof(int) * (NN + 1));
    int*   cursor     = (int*)  take(sizeof(int) * NN);
    int*   part       = (int*)  take(sizeof(int) * 256);
    int2*  epack      = (int2*) take(sizeof(int2) * EE);
    float* xlr        = (float*)take(sizeof(float) * (size_t)NN * 256);
    float* h0         = (float*)take(sizeof(float) * (size_t)NN * 128);
    float* h1         = (float*)take(sizeof(float) * (size_t)NN * 128);

    // --- CSR build ---
    hipMemsetAsync(cursor, 0, sizeof(int) * NN, stream);
    hist_kernel<<<EE / 256, 256, 0, stream>>>(ei + EE, cursor);
    scan_part<<<256, 256, 0, stream>>>(cursor, part);
    scan_block<<<1, 256, 0, stream>>>(part);
    scan_final<<<256, 256, 0, stream>>>(cursor, part, row_start);
    scatter_kernel<<<EE / 256, 256, 0, stream>>>(ei, ea, cursor, epack);

    const int GB = (NN + 127) / 128;  // 391
    dim3 gdual(GB, 2);

    // --- layer 1 ---
    gemm_dual<<<gdual, 256, 0, stream>>>(x, l1_Wl, l1_Wr, xlr, NN);
    node_agg_128<<<(NN * 64) / 256, 256, 0, stream>>>(
        xlr, row_start, epack, l1_We, l1_att, l1_b,
        bn_g, bn_b, bn_m, bn_v, h0);

    // --- layers 2-9 ---
    float* hin = h0;
    float* hout = h1;
    for (int i = 0; i < 8; ++i) {
        gemm_dual<<<gdual, 256, 0, stream>>>(hin, mid_Wl + (size_t)i * 128 * 128,
                                             mid_Wr + (size_t)i * 128 * 128, xlr, NN);
        node_agg_128<<<(NN * 64) / 256, 256, 0, stream>>>(
            xlr, row_start, epack,
            mid_We + (size_t)i * 128, mid_att + (size_t)i * 128, mid_b + (size_t)i * 128,
            bn_g + (size_t)(i + 1) * 128, bn_b + (size_t)(i + 1) * 128,
            bn_m + (size_t)(i + 1) * 128, bn_v + (size_t)(i + 1) * 128, hout);
        float* tmp = hin; hin = hout; hout = tmp;
    }

    // --- layer 10 (xlr reused as [N][64]) ---
    const int MB = (NN + 63) / 64;  // 782
    dim3 g1(MB, 1);
    gemm_tile<<<g1, 256, 0, stream>>>(hin, l10_Wl, xlr, NN, 32, 32, 64, 0);
    gemm_tile<<<g1, 256, 0, stream>>>(hin, l10_Wr, xlr, NN, 32, 32, 64, 32);
    node_agg_l10<<<(NN * 32 + 255) / 256, 256, 0, stream>>>(
        xlr, row_start, epack, l10_We, l10_att, l10_b,
        bn10_g, bn10_b, bn10_m, bn10_v, lin_W, lin_b, (float*)d_out);
}